// Round 2
// baseline (154.086 us; speedup 1.0000x reference)
//
#include <hip/hip_runtime.h>
#include <hip/hip_bf16.h>

// Problem constants
#define SEQ   4096
#define DM    1024
#define NH    16
#define HD    64
#define N3    3072       // 3*DM
#define WIN   512

#define LOG2E 1.4426950408889634f

typedef __attribute__((ext_vector_type(8))) short short8;   // 8 bf16 (4 VGPRs)
typedef __attribute__((ext_vector_type(4))) short short4v;  // 4 bf16 (8B)
typedef __attribute__((ext_vector_type(4))) float float4v;  // 4 fp32 acc

__device__ __forceinline__ float bf16_bits_to_float(unsigned short u) {
  return __uint_as_float(((unsigned int)u) << 16);
}

// async 16B global->LDS (m97 path: emits global_load_lds_dwordx4)
typedef __attribute__((address_space(3))) void lds_void_t;
typedef __attribute__((address_space(1))) const void gbl_void_t;
__device__ __forceinline__ void async_copy16(void* lds_dst, const void* g_src) {
  __builtin_amdgcn_global_load_lds((gbl_void_t*)g_src, (lds_void_t*)lds_dst,
                                   16, 0, 0);
}

// ---------------------------------------------------------------------------
// Block-level dtype detection (LDS reduction): 1 = fp32 inputs, 0 = bf16.
// ---------------------------------------------------------------------------
template <int NT>
__device__ __forceinline__ int detect_fp32(const unsigned short* __restrict__ probe,
                                           float* red) {
  const int t = threadIdx.x;
  float mx = 0.0f;
#pragma unroll
  for (int p = 0; p < 8; ++p) {
    float v = bf16_bits_to_float(probe[(t * 8 + p) * 2]);
    if (v != v) v = 1e38f;
    mx = fmaxf(mx, fabsf(v));
  }
  red[t] = mx;
  __syncthreads();
  for (int s = NT / 2; s > 0; s >>= 1) {
    if (t < s) red[t] = fmaxf(red[t], red[t + s]);
    __syncthreads();
  }
  const int fl = red[0] > 100.0f ? 1 : 0;
  __syncthreads();
  return fl;
}

// Wave-level dtype detection (no LDS, no barriers).
__device__ __forceinline__ int detect_fp32_wave(
    const unsigned short* __restrict__ probe) {
  const int lane = threadIdx.x & 63;
  float mx = 0.0f;
#pragma unroll
  for (int p = 0; p < 8; ++p) {
    float v = bf16_bits_to_float(probe[(lane * 8 + p) * 2]);
    if (v != v) v = 1e38f;
    mx = fmaxf(mx, fabsf(v));
  }
  return __any(mx > 100.0f) ? 1 : 0;
}

// ---------------------------------------------------------------------------
// Kernel 1 (merged prep): blocks [0,2048) convert X -> xb bf16;
// blocks [2048, 2816) transpose/convert W -> WT bf16.
// ---------------------------------------------------------------------------
__global__ __launch_bounds__(256) void prep(
    const void* __restrict__ x, const void* __restrict__ w,
    __hip_bfloat16* __restrict__ xb, __hip_bfloat16* __restrict__ wt) {
  __shared__ __hip_bfloat16 tile[64][66];
  __shared__ float red[256];
  const int t = threadIdx.x;
  if (blockIdx.x < 2048) {
    const int fl = detect_fp32<256>((const unsigned short*)x, red);
    const int i0 = (blockIdx.x * 256 + t) * 8;
    if (fl) {
      const float* xf = (const float*)x + i0;
      float4 f0 = *(const float4*)(xf);
      float4 f1 = *(const float4*)(xf + 4);
      __hip_bfloat16 tmp[8];
      tmp[0] = __float2bfloat16(f0.x); tmp[1] = __float2bfloat16(f0.y);
      tmp[2] = __float2bfloat16(f0.z); tmp[3] = __float2bfloat16(f0.w);
      tmp[4] = __float2bfloat16(f1.x); tmp[5] = __float2bfloat16(f1.y);
      tmp[6] = __float2bfloat16(f1.z); tmp[7] = __float2bfloat16(f1.w);
      *(uint4*)&xb[i0] = *(const uint4*)tmp;
    } else {
      *(uint4*)&xb[i0] = *(const uint4*)((const __hip_bfloat16*)x + i0);
    }
  } else {
    const int bid = blockIdx.x - 2048;
    const int fl = detect_fp32<256>((const unsigned short*)w, red);
    const int n0 = (bid % 48) * 64;
    const int k0 = (bid / 48) * 64;
    const int tx = t & 63, ty0 = t >> 6;
    if (fl) {
      const float* wf = (const float*)w;
#pragma unroll
      for (int p = 0; p < 16; ++p) {
        int row = ty0 + p * 4;
        tile[row][tx] = __float2bfloat16(wf[(k0 + row) * N3 + n0 + tx]);
      }
    } else {
      const __hip_bfloat16* wb = (const __hip_bfloat16*)w;
#pragma unroll
      for (int p = 0; p < 16; ++p) {
        int row = ty0 + p * 4;
        tile[row][tx] = wb[(k0 + row) * N3 + n0 + tx];
      }
    }
    __syncthreads();
#pragma unroll
    for (int r = 0; r < 2; ++r) {
      int oe = r * 2048 + t * 8;
      int nr = oe >> 6, kc = oe & 63;
      __hip_bfloat16 v[8];
#pragma unroll
      for (int e = 0; e < 8; ++e) v[e] = tile[kc + e][nr];
      *(uint4*)&wt[(n0 + nr) * DM + k0 + kc] = *(const uint4*)v;
    }
  }
}

// ---------------------------------------------------------------------------
// Kernel 2 (ROUND 15): KQV = xb[4096,1024] * WT^T -> bf16 [4096,3072].
// T3+T4+T5 stack: 256x256 tile, BK=32, 8 waves (2Mx4N), TRIPLE-buffered LDS
// (96 KB -> 1 block/CU, 2 waves/SIMD), counted vmcnt(4) (never 0 in steady
// state), raw s_barrier (no __syncthreads drain), setprio around MFMA.
// Race-freedom by construction: stage K-tile kt+2 into buf (kt+2)%3 while
// reading kt%3 and kt+1 holds (kt+1)%3 -- always disjoint. Per K-tile end,
// vmcnt(4) confirms the 2 oldest units = exactly K-tile kt+1's A and B
// (each wave's own slices), then s_barrier makes them globally visible.
// BK=32 rows are 64 B, so frag ds_read_b128 is conflict-free w/o swizzle.
// Grid 12x16 = 192 blocks (XCD-bijective swizzle, 192%8==0).
// ---------------------------------------------------------------------------
__global__ __launch_bounds__(512, 2) void gemm_kqv(
    const __hip_bfloat16* __restrict__ A,    // xb [4096][1024]
    const __hip_bfloat16* __restrict__ BT,   // WT [3072][1024]
    __hip_bfloat16* __restrict__ C) {        // kqv [4096][3072]
  __shared__ __align__(16) __hip_bfloat16 As[3][256 * 32];  // 48 KB
  __shared__ __align__(16) __hip_bfloat16 Bs[3][256 * 32];  // 48 KB

  const int flat = blockIdx.y * 12 + blockIdx.x;   // 0..191
  const int swz  = (flat & 7) * 24 + (flat >> 3);  // XCD chunking, bijective
  const int m0 = (swz / 12) * 256;
  const int n0 = (swz % 12) * 256;

  const int t = threadIdx.x;
  const int wave = t >> 6, lane = t & 63;
  const int wm = wave >> 2, wn = wave & 3;        // 2 x 4 wave grid
  const int l15 = lane & 15, quad = lane >> 4;

  // staging: thread t covers rows {srow, 128+srow} of a 256x32 unit
  const int srow = t >> 2;          // 0..127
  const int scol = (t & 3) * 8;     // bf16 col within BK=32
  const __hip_bfloat16* gA0 = &A [(m0 +       srow) * DM + scol];
  const __hip_bfloat16* gA1 = &A [(m0 + 128 + srow) * DM + scol];
  const __hip_bfloat16* gB0 = &BT[(n0 +       srow) * DM + scol];
  const __hip_bfloat16* gB1 = &BT[(n0 + 128 + srow) * DM + scol];
  const int ldst = t * 16;          // linear LDS byte offset (matches srow/scol)

#define STAGE_A(buf, kt) do { \
    const int ko_ = (kt) * 32; \
    async_copy16((char*)As[buf] + ldst,        gA0 + ko_); \
    async_copy16((char*)As[buf] + 8192 + ldst, gA1 + ko_); } while (0)
#define STAGE_B(buf, kt) do { \
    const int ko_ = (kt) * 32; \
    async_copy16((char*)Bs[buf] + ldst,        gB0 + ko_); \
    async_copy16((char*)Bs[buf] + 8192 + ldst, gB1 + ko_); } while (0)

  const int arow = wm * 128 + l15;   // + mi*16 (+64 for upper half)
  const int brow = wn * 64 + l15;    // + ni*16
  const int kbyte = quad * 16;       // 16B k-slice within 64B row

  float4v acc[8][4] = {};

  // prologue: K-tiles 0 and 1 in flight; confirm tile 0 before first read
  STAGE_A(0, 0); STAGE_B(0, 0);
  STAGE_A(1, 1); STAGE_B(1, 1);
  asm volatile("s_waitcnt vmcnt(4)" ::: "memory");
  __builtin_amdgcn_s_barrier();

  for (int kt = 0; kt < 32; ++kt) {
    const int cur = kt % 3;
    const int nb  = (kt + 2) % 3;
    const char* Ac = (const char*)As[cur];
    const char* Bc = (const char*)Bs[cur];
    short8 a[4], b[4];

    // ---- phase 0: lower m-half ----
    if (kt < 30) STAGE_A(nb, kt + 2);
#pragma unroll
    for (int mi = 0; mi < 4; ++mi)
      a[mi] = *(const short8*)(Ac + (arow + mi * 16) * 64 + kbyte);
#pragma unroll
    for (int ni = 0; ni < 4; ++ni)
      b[ni] = *(const short8*)(Bc + (brow + ni * 16) * 64 + kbyte);
    __builtin_amdgcn_s_barrier();
    __builtin_amdgcn_s_setprio(1);
#pragma unroll
    for (int mi = 0; mi < 4; ++mi)
#pragma unroll
      for (int ni = 0; ni < 4; ++ni)
        acc[mi][ni] = __builtin_amdgcn_mfma_f32_16x16x32_bf16(
            a[mi], b[ni], acc[mi][ni], 0, 0, 0);
    __builtin_amdgcn_s_setprio(0);

    // ---- phase 1: upper m-half (B frags reused from registers) ----
    if (kt < 30) STAGE_B(nb, kt + 2);
#pragma unroll
    for (int mi = 0; mi < 4; ++mi)
      a[mi] = *(const short8*)(Ac + (arow + 64 + mi * 16) * 64 + kbyte);
    __builtin_amdgcn_s_barrier();
    __builtin_amdgcn_s_setprio(1);
#pragma unroll
    for (int mi = 0; mi < 4; ++mi)
#pragma unroll
      for (int ni = 0; ni < 4; ++ni)
        acc[4 + mi][ni] = __builtin_amdgcn_mfma_f32_16x16x32_bf16(
            a[mi], b[ni], acc[4 + mi][ni], 0, 0, 0);
    __builtin_amdgcn_s_setprio(0);

    // ---- K-tile boundary: confirm kt+1's units, then publish ----
    if (kt <= 28) asm volatile("s_waitcnt vmcnt(4)" ::: "memory");
    else          asm volatile("s_waitcnt vmcnt(0)" ::: "memory");
    __builtin_amdgcn_s_barrier();
  }
#undef STAGE_A
#undef STAGE_B

  // ---- epilogue: C[row][col], row from quad*4+r, col from l15 ----
#pragma unroll
  for (int mi = 0; mi < 8; ++mi)
#pragma unroll
    for (int ni = 0; ni < 4; ++ni)
#pragma unroll
      for (int r = 0; r < 4; ++r) {
        int row = m0 + wm * 128 + mi * 16 + quad * 4 + r;
        int col = n0 + wn * 64 + ni * 16 + l15;
        C[row * N3 + col] = __float2bfloat16(acc[mi][ni][r]);
      }
}

// ---------------------------------------------------------------------------
// Kernel 3: MFMA flash attention, fixed-max softmax (m=0).
// ROUND 14 structure (verified): sigma(k) permutation on P/V, swizzled Vt,
// b64 softmax stores, b128 V reads. Round-11 plateau config otherwise:
// 64-q tiles / 256 thr / single-buffer LDS / 4 blocks/CU / register prefetch
// issued after the second barrier.
// ---------------------------------------------------------------------------
__global__ __launch_bounds__(256, 4) void attn(
    const __hip_bfloat16* __restrict__ kqv,
    const unsigned short* __restrict__ xprobe,   // d_in[0], dtype probe only
    void* __restrict__ out) {
  __shared__ __align__(16) __hip_bfloat16 Ks[64 * 72];  // [k][d]
  __shared__ __align__(16) __hip_bfloat16 Vt[80 * 72];  // [d][p]; row 64 ones, 65..79 zero
  __shared__ __align__(16) __hip_bfloat16 Ps[64 * 72];  // [q][p] (wave-private strips)

  const int fl = detect_fp32_wave(xprobe);     // no barriers, no LDS
  const int h  = blockIdx.y;
  const int bx = blockIdx.x;
  const int i0 = 64 * ((bx & 7) * 8 + (bx >> 3));
  const int t    = threadIdx.x;
  const int wave = t >> 6, lane = t & 63;
  const int l15 = lane & 15, quad = lane >> 4;
  const float slope2  = exp2f(-0.5f * (float)(h + 1)) * LOG2E;  // m_h*log2(e)
  const float nslope2 = -slope2;                                // bias = nslope2*(i-j)
  const float qscale  = LOG2E / 32.0f;

  // ones/zero rows of Vt: row-uniform content, swizzle-invariant: write linear.
  for (int idx = t; idx < 16 * 64; idx += 256) {
    int rr = idx >> 6, cc = idx & 63;
    ((unsigned short*)Vt)[(64 + rr) * 72 + cc] = (rr == 0) ? 0x3F80 : 0;
  }

  // Q fragments direct to registers: A[m=l15][k=quad*8+j], rows wave*16+l15
  short8 aq[2];
#pragma unroll
  for (int ks2 = 0; ks2 < 2; ++ks2)
    aq[ks2] = *(const short8*)&kqv[(i0 + wave * 16 + l15) * N3 + DM + h * HD +
                                   ks2 * 32 + quad * 8];

  float4v o[5] = {};   // o[dt][r]: row quad*4+r, col dt*16+l15; dt=4 is l-column

  const int jlo  = max(0, i0 - WIN);       // 64-aligned
  const int nblk = (i0 + 64 - jlo) >> 6;   // <= 9

  // ---- staging geometry + prefetch of block 0 ----
  const int krow0 = t >> 3, krow1 = (t >> 3) + 32, kd0 = (t & 7) * 8;
  const int rbase = t >> 3;                              // 0..31
  const int vd0   = (t & 7) * 8;
  const int kA    = (rbase & 15) + ((rbase >> 4) << 5);  // {0..15, 32..47}
  const int vsig2 = (((rbase & 15) << 2) + ((rbase >> 4) << 1)) * 2; // byte pos of sigma(kA)
  const int vswz  = (t & 7) << 4;  // = ((row>>3)&7)<<4 for rows vd0..vd0+7
  uint4 kregA, kregB, vregA, vregB;
  kregA = *(const uint4*)&kqv[(jlo + krow0) * N3 + h * HD + kd0];
  kregB = *(const uint4*)&kqv[(jlo + krow1) * N3 + h * HD + kd0];
  vregA = *(const uint4*)&kqv[(jlo + kA) * N3 + 2 * DM + h * HD + vd0];
  vregB = *(const uint4*)&kqv[(jlo + kA + 16) * N3 + 2 * DM + h * HD + vd0];

  for (int b = 0; b < nblk; ++b) {
    const int j0 = jlo + b * 64;
    __syncthreads();   // prev iter's K/V readers done before overwrite
    // ---- LDS fill from prefetched registers ----
    *(uint4*)&Ks[krow0 * 72 + kd0] = kregA;
    *(uint4*)&Ks[krow1 * 72 + kd0] = kregB;
    {
      const unsigned short* pa = (const unsigned short*)&vregA;
      const unsigned short* pb = (const unsigned short*)&vregB;
      char* vbase = (char*)Vt;
#pragma unroll
      for (int e = 0; e < 8; ++e) {
        unsigned int pack = (unsigned int)pa[e] | ((unsigned int)pb[e] << 16);
        *(unsigned int*)(vbase + (vd0 + e) * 144 + (vsig2 ^ vswz)) = pack;
      }
    }
    __syncthreads();   // nothing outstanding here: prefetch not yet issued

    // ---- issue next block's prefetch NOW (covered by compute below) ----
    if (b + 1 < nblk) {
      const int jn = j0 + 64;
      kregA = *(const uint4*)&kqv[(jn + krow0) * N3 + h * HD + kd0];
      kregB = *(const uint4*)&kqv[(jn + krow1) * N3 + h * HD + kd0];
      vregA = *(const uint4*)&kqv[(jn + kA) * N3 + 2 * DM + h * HD + vd0];
      vregB = *(const uint4*)&kqv[(jn + kA + 16) * N3 + 2 * DM + h * HD + vd0];
    }

    // ---- S = Q*K^T : 4 n-tiles x 2 k-steps ----
    float4v sacc[4] = {};
#pragma unroll
    for (int ks2 = 0; ks2 < 2; ++ks2)
#pragma unroll
      for (int nt = 0; nt < 4; ++nt) {
        short8 bk = *(const short8*)&Ks[(nt * 16 + l15) * 72 + ks2 * 32 + quad * 8];
        sacc[nt] = __builtin_amdgcn_mfma_f32_16x16x32_bf16(aq[ks2], bk, sacc[nt], 0, 0, 0);
      }

    // ---- fixed-max softmax: p = exp2(x), masked -> 0 ----
    // Lane computes S[q][k = nt*16+l15]; stored at p = sigma(k) = l15*4 + nt.
    const int dbase = (i0 + wave * 16 + quad * 4) - (j0 + l15);
    const float s16 = nslope2 * -16.0f;   // bias step per nt
    const int psbase = (wave * 16 + quad * 4) * 72 + l15 * 4;
#pragma unroll
    for (int r = 0; r < 4; ++r) {
      float bias = nslope2 * (float)(dbase + r);
      int rel = dbase + r;
      short4v pk;
#pragma unroll
      for (int nt = 0; nt < 4; ++nt) {
        float x = fmaf(sacc[nt][r], qscale, bias);
        x = ((unsigned)rel <= (unsigned)WIN) ? x : -200.0f;  // exp2(-200)==0
        __hip_bfloat16 hb = __float2bfloat16(exp2f(x));
        pk[nt] = *reinterpret_cast<const short*>(&hb);
        bias += s16;
        rel -= 16;
      }
      *(short4v*)&Ps[psbase + r * 72] = pk;
    }
    // no barrier: Ps strip is wave-private

    // ---- O += P*V (dt 0..3) ; l += P*1 (dt 4, ones-row of Vt) ----
#pragma unroll
    for (int ks = 0; ks < 64; ks += 32) {
      short8 ap = *(const short8*)&Ps[(wave * 16 + l15) * 72 + ks + quad * 8];
#pragma unroll
      for (int dt = 0; dt < 5; ++dt) {
        const int vrow = dt * 16 + l15;
        const short8 bv = *(const short8*)((const char*)Vt + vrow * 144 +
            ((ks * 2 + (quad << 4)) ^ (((vrow >> 3) & 7) << 4)));
        o[dt] = __builtin_amdgcn_mfma_f32_16x16x32_bf16(ap, bv, o[dt], 0, 0, 0);
      }
    }
  }

  // ---- epilogue: l lives in o[4] col 0 (lane l15==0 of each quad group) ----
#pragma unroll
  for (int r = 0; r < 4; ++r) {
    const float l = __shfl(o[4][r], quad * 16, 64);   // broadcast from l15==0 lane
    const float inv_l = 1.0f / l;    // l >= 2^-2: diagonal key j=i always valid
    const int row = i0 + wave * 16 + quad * 4 + r;
#pragma unroll
    for (int dt = 0; dt < 4; ++dt) {
      const int idx = row * DM + h * HD + dt * 16 + l15;
      const float v = o[dt][r] * inv_l;
      if (fl) ((float*)out)[idx] = v;
      else    ((__hip_bfloat16*)out)[idx] = __float2bfloat16(v);
    }
  }
}

// ---------------------------------------------------------------------------
extern "C" void kernel_launch(void* const* d_in, const int* in_sizes, int n_in,
                              void* d_out, int out_size, void* d_ws, size_t ws_size,
                              hipStream_t stream) {
  char* ws = (char*)d_ws;
  __hip_bfloat16* wt  = (__hip_bfloat16*)(ws + 4096);          // 6 MB
  __hip_bfloat16* kqv = (__hip_bfloat16*)(ws + 4096 + 6291456);// 24 MB
  // xb lives in d_out's first 8 MB: dead until attn's epilogue overwrites all
  // of d_out, and gemm_kqv (the only xb reader) completes before attn runs.
  __hip_bfloat16* xb  = (__hip_bfloat16*)d_out;

  hipLaunchKernelGGL(prep, dim3(2048 + 768), dim3(256), 0, stream,
                     d_in[0], d_in[1], xb, wt);
  hipLaunchKernelGGL(gemm_kqv, dim3(12, 16), dim3(512), 0, stream, xb, wt, kqv);
  hipLaunchKernelGGL(attn, dim3(64, 16), dim3(256), 0, stream,
                     kqv, (const unsigned short*)d_in[0], d_out);
}

// Round 4
// 141.711 us; speedup vs baseline: 1.0873x; 1.0873x over previous
//
#include <hip/hip_runtime.h>
#include <hip/hip_bf16.h>

// Problem constants
#define SEQ   4096
#define DM    1024
#define NH    16
#define HD    64
#define N3    3072       // 3*DM
#define WIN   512

#define LOG2E 1.4426950408889634f

typedef __attribute__((ext_vector_type(8))) short short8;   // 8 bf16 (4 VGPRs)
typedef __attribute__((ext_vector_type(4))) short short4v;  // 4 bf16 (8B)
typedef __attribute__((ext_vector_type(4))) float float4v;  // 4 fp32 acc

__device__ __forceinline__ float bf16_bits_to_float(unsigned short u) {
  return __uint_as_float(((unsigned int)u) << 16);
}

// async 16B global->LDS (m97 path: emits global_load_lds_dwordx4)
typedef __attribute__((address_space(3))) void lds_void_t;
typedef __attribute__((address_space(1))) const void gbl_void_t;
__device__ __forceinline__ void async_copy16(void* lds_dst, const void* g_src) {
  __builtin_amdgcn_global_load_lds((gbl_void_t*)g_src, (lds_void_t*)lds_dst,
                                   16, 0, 0);
}

// ---------------------------------------------------------------------------
// Block-level dtype detection (LDS reduction): 1 = fp32 inputs, 0 = bf16.
// ---------------------------------------------------------------------------
template <int NT>
__device__ __forceinline__ int detect_fp32(const unsigned short* __restrict__ probe,
                                           float* red) {
  const int t = threadIdx.x;
  float mx = 0.0f;
#pragma unroll
  for (int p = 0; p < 8; ++p) {
    float v = bf16_bits_to_float(probe[(t * 8 + p) * 2]);
    if (v != v) v = 1e38f;
    mx = fmaxf(mx, fabsf(v));
  }
  red[t] = mx;
  __syncthreads();
  for (int s = NT / 2; s > 0; s >>= 1) {
    if (t < s) red[t] = fmaxf(red[t], red[t + s]);
    __syncthreads();
  }
  const int fl = red[0] > 100.0f ? 1 : 0;
  __syncthreads();
  return fl;
}

// Wave-level dtype detection (no LDS, no barriers).
__device__ __forceinline__ int detect_fp32_wave(
    const unsigned short* __restrict__ probe) {
  const int lane = threadIdx.x & 63;
  float mx = 0.0f;
#pragma unroll
  for (int p = 0; p < 8; ++p) {
    float v = bf16_bits_to_float(probe[(lane * 8 + p) * 2]);
    if (v != v) v = 1e38f;
    mx = fmaxf(mx, fabsf(v));
  }
  return __any(mx > 100.0f) ? 1 : 0;
}

// ---------------------------------------------------------------------------
// Kernel 1 (merged prep): blocks [0,2048) convert X -> xb bf16;
// blocks [2048, 2816) transpose/convert W -> WT bf16.
// ---------------------------------------------------------------------------
__global__ __launch_bounds__(256) void prep(
    const void* __restrict__ x, const void* __restrict__ w,
    __hip_bfloat16* __restrict__ xb, __hip_bfloat16* __restrict__ wt) {
  __shared__ __hip_bfloat16 tile[64][66];
  __shared__ float red[256];
  const int t = threadIdx.x;
  if (blockIdx.x < 2048) {
    const int fl = detect_fp32<256>((const unsigned short*)x, red);
    const int i0 = (blockIdx.x * 256 + t) * 8;
    if (fl) {
      const float* xf = (const float*)x + i0;
      float4 f0 = *(const float4*)(xf);
      float4 f1 = *(const float4*)(xf + 4);
      __hip_bfloat16 tmp[8];
      tmp[0] = __float2bfloat16(f0.x); tmp[1] = __float2bfloat16(f0.y);
      tmp[2] = __float2bfloat16(f0.z); tmp[3] = __float2bfloat16(f0.w);
      tmp[4] = __float2bfloat16(f1.x); tmp[5] = __float2bfloat16(f1.y);
      tmp[6] = __float2bfloat16(f1.z); tmp[7] = __float2bfloat16(f1.w);
      *(uint4*)&xb[i0] = *(const uint4*)tmp;
    } else {
      *(uint4*)&xb[i0] = *(const uint4*)((const __hip_bfloat16*)x + i0);
    }
  } else {
    const int bid = blockIdx.x - 2048;
    const int fl = detect_fp32<256>((const unsigned short*)w, red);
    const int n0 = (bid % 48) * 64;
    const int k0 = (bid / 48) * 64;
    const int tx = t & 63, ty0 = t >> 6;
    if (fl) {
      const float* wf = (const float*)w;
#pragma unroll
      for (int p = 0; p < 16; ++p) {
        int row = ty0 + p * 4;
        tile[row][tx] = __float2bfloat16(wf[(k0 + row) * N3 + n0 + tx]);
      }
    } else {
      const __hip_bfloat16* wb = (const __hip_bfloat16*)w;
#pragma unroll
      for (int p = 0; p < 16; ++p) {
        int row = ty0 + p * 4;
        tile[row][tx] = wb[(k0 + row) * N3 + n0 + tx];
      }
    }
    __syncthreads();
#pragma unroll
    for (int r = 0; r < 2; ++r) {
      int oe = r * 2048 + t * 8;
      int nr = oe >> 6, kc = oe & 63;
      __hip_bfloat16 v[8];
#pragma unroll
      for (int e = 0; e < 8; ++e) v[e] = tile[kc + e][nr];
      *(uint4*)&wt[(n0 + nr) * DM + k0 + kc] = *(const uint4*)v;
    }
  }
}

// ---------------------------------------------------------------------------
// Kernel 2 (ROUND 17 = ROUND 16 with launch_bounds(512,2)):
// KQV = xb[4096,1024] * WT^T -> bf16 [4096,3072].
// T2+T3+T4+T5 on a coverage-exact geometry:
//   BM=128 BN=192 BK=64, grid 32x16 = 512 blocks = EXACTLY 2 blocks/CU
//   (LDS-bound: 80KB dbuf). 8 waves (2m x 4n), per-wave out 64x48 (acc[4][3]).
// 2 phases/K-tile, each: {7x ds_read_b128 || stage units || vmcnt(N) ||
//   s_barrier || setprio + 12 MFMA || setprio(0) || s_barrier}.
// Stage units = 8KB (1 load/thread, wave-uniform). Order per tile kt+1:
//   ph0 stages B u0,u1,u2 ; ph1 stages A kh0,kh1.
// Derived counted waits (never drain in steady state):
//   ph0: vmcnt(3)  -> confirms A-kh1(kt), leaves B x3(kt+1) in flight
//   ph1: vmcnt(1)  -> confirms B x3(kt+1)+A-kh0(kt+1), leaves A-kh1(kt+1)
//   last tile: ph0 vmcnt(0).
// T2 swizzle per rule #21 (linear LDS dest, inverse-swizzled global SOURCE,
// same XOR on ds_read): A (64B rows) c16 ^= row&3 (4-way max);
// B (128B rows) c16 ^= row&7 (2 lanes/bank = free).
// ---------------------------------------------------------------------------
__global__ __launch_bounds__(512, 2) void gemm_kqv(
    const __hip_bfloat16* __restrict__ A,    // xb [4096][1024]
    const __hip_bfloat16* __restrict__ BT,   // WT [3072][1024]
    __hip_bfloat16* __restrict__ C) {        // kqv [4096][3072]
  __shared__ __align__(16) __hip_bfloat16 As[2][2][128 * 32]; // [buf][khalf] 8KB
  __shared__ __align__(16) __hip_bfloat16 Bs[2][192 * 64];    // [buf] 24KB (3 units)

  const int flat = blockIdx.y * 16 + blockIdx.x;   // 0..511
  const int swz  = (flat & 7) * 64 + (flat >> 3);  // XCD chunked, bijective
  const int m0 = (swz >> 4) * 128;                 // 32 m-tiles
  const int n0 = (swz & 15) * 192;                 // 16 n-tiles

  const int t = threadIdx.x;
  const int wave = t >> 6, lane = t & 63;
  const int wm = wave >> 2, wn = wave & 3;         // 2 x 4 wave grid
  const int l15 = lane & 15, quad = lane >> 4;

  // staging geometry (all units 8KB = 1 load/thread)
  const int arow = t >> 2;                              // 0..127
  const int acol = ((t & 3) ^ (arow & 3)) * 8;          // inverse-swizzled src col
  const long aoff = (long)(m0 + arow) * DM + acol;
  const int brow = t >> 3;                              // 0..63 (local in unit)
  const int bcol = ((t & 7) ^ (brow & 7)) * 8;
  const long boff0 = (long)(n0 +       brow) * DM + bcol;
  const long boff1 = (long)(n0 +  64 + brow) * DM + bcol;
  const long boff2 = (long)(n0 + 128 + brow) * DM + bcol;
  const int ldst = t * 16;

#define STAGE_B(buf, kt) do { \
    const int ko_ = (kt) * 64; \
    async_copy16((char*)Bs[buf]         + ldst, &BT[boff0 + ko_]); \
    async_copy16((char*)Bs[buf] +  8192 + ldst, &BT[boff1 + ko_]); \
    async_copy16((char*)Bs[buf] + 16384 + ldst, &BT[boff2 + ko_]); } while (0)
#define STAGE_A(buf, kt) do { \
    const int ko_ = (kt) * 64; \
    async_copy16((char*)As[buf][0] + ldst, &A[aoff + ko_]); \
    async_copy16((char*)As[buf][1] + ldst, &A[aoff + ko_ + 32]); } while (0)

  float4v acc[4][3] = {};

  // prologue: tile 0 fully staged + drained
  STAGE_B(0, 0); STAGE_A(0, 0);
  asm volatile("s_waitcnt vmcnt(0)" ::: "memory");
  __builtin_amdgcn_s_barrier();

  for (int kt = 0; kt < 16; ++kt) {
    const int P = kt & 1, N = P ^ 1;
    short8 a[4], b[3];

#pragma unroll
    for (int h = 0; h < 2; ++h) {
      const char* Ap = (const char*)As[P][h];
      const char* Bp = (const char*)Bs[P];
      // ds_read current phase's fragments (swizzled cols)
#pragma unroll
      for (int mi = 0; mi < 4; ++mi) {
        const int row = wm * 64 + mi * 16 + l15;
        a[mi] = *(const short8*)(Ap + row * 64 + ((quad ^ (row & 3)) << 4));
      }
#pragma unroll
      for (int ni = 0; ni < 3; ++ni) {
        const int row = wn * 48 + ni * 16 + l15;
        b[ni] = *(const short8*)(Bp + row * 128 +
                                 ((((h << 2) + quad) ^ (row & 7)) << 4));
      }
      // stage next tile's units + counted wait
      if (h == 0) {
        if (kt < 15) {
          STAGE_B(N, kt + 1);
          asm volatile("s_waitcnt vmcnt(3)" ::: "memory");
        } else {
          asm volatile("s_waitcnt vmcnt(0)" ::: "memory");
        }
      } else {
        if (kt < 15) STAGE_A(N, kt + 1);
        asm volatile("s_waitcnt vmcnt(1)" ::: "memory");
      }
      __builtin_amdgcn_s_barrier();
      __builtin_amdgcn_s_setprio(1);
#pragma unroll
      for (int mi = 0; mi < 4; ++mi)
#pragma unroll
        for (int ni = 0; ni < 3; ++ni)
          acc[mi][ni] = __builtin_amdgcn_mfma_f32_16x16x32_bf16(
              a[mi], b[ni], acc[mi][ni], 0, 0, 0);
      __builtin_amdgcn_s_setprio(0);
      __builtin_amdgcn_s_barrier();
    }
  }
#undef STAGE_A
#undef STAGE_B

  // ---- epilogue: C[row][col], row from quad*4+r, col from l15 ----
#pragma unroll
  for (int mi = 0; mi < 4; ++mi)
#pragma unroll
    for (int ni = 0; ni < 3; ++ni)
#pragma unroll
      for (int r = 0; r < 4; ++r) {
        int row = m0 + wm * 64 + mi * 16 + quad * 4 + r;
        int col = n0 + wn * 48 + ni * 16 + l15;
        C[row * N3 + col] = __float2bfloat16(acc[mi][ni][r]);
      }
}

// ---------------------------------------------------------------------------
// Kernel 3: MFMA flash attention, fixed-max softmax (m=0).
// ROUND 14 structure (verified): sigma(k) permutation on P/V, swizzled Vt,
// b64 softmax stores, b128 V reads. Round-11 plateau config otherwise:
// 64-q tiles / 256 thr / single-buffer LDS / 4 blocks/CU / register prefetch
// issued after the second barrier.
// ---------------------------------------------------------------------------
__global__ __launch_bounds__(256, 4) void attn(
    const __hip_bfloat16* __restrict__ kqv,
    const unsigned short* __restrict__ xprobe,   // d_in[0], dtype probe only
    void* __restrict__ out) {
  __shared__ __align__(16) __hip_bfloat16 Ks[64 * 72];  // [k][d]
  __shared__ __align__(16) __hip_bfloat16 Vt[80 * 72];  // [d][p]; row 64 ones, 65..79 zero
  __shared__ __align__(16) __hip_bfloat16 Ps[64 * 72];  // [q][p] (wave-private strips)

  const int fl = detect_fp32_wave(xprobe);     // no barriers, no LDS
  const int h  = blockIdx.y;
  const int bx = blockIdx.x;
  const int i0 = 64 * ((bx & 7) * 8 + (bx >> 3));
  const int t    = threadIdx.x;
  const int wave = t >> 6, lane = t & 63;
  const int l15 = lane & 15, quad = lane >> 4;
  const float slope2  = exp2f(-0.5f * (float)(h + 1)) * LOG2E;  // m_h*log2(e)
  const float nslope2 = -slope2;                                // bias = nslope2*(i-j)
  const float qscale  = LOG2E / 32.0f;

  // ones/zero rows of Vt: row-uniform content, swizzle-invariant: write linear.
  for (int idx = t; idx < 16 * 64; idx += 256) {
    int rr = idx >> 6, cc = idx & 63;
    ((unsigned short*)Vt)[(64 + rr) * 72 + cc] = (rr == 0) ? 0x3F80 : 0;
  }

  // Q fragments direct to registers: A[m=l15][k=quad*8+j], rows wave*16+l15
  short8 aq[2];
#pragma unroll
  for (int ks2 = 0; ks2 < 2; ++ks2)
    aq[ks2] = *(const short8*)&kqv[(i0 + wave * 16 + l15) * N3 + DM + h * HD +
                                   ks2 * 32 + quad * 8];

  float4v o[5] = {};   // o[dt][r]: row quad*4+r, col dt*16+l15; dt=4 is l-column

  const int jlo  = max(0, i0 - WIN);       // 64-aligned
  const int nblk = (i0 + 64 - jlo) >> 6;   // <= 9

  // ---- staging geometry + prefetch of block 0 ----
  const int krow0 = t >> 3, krow1 = (t >> 3) + 32, kd0 = (t & 7) * 8;
  const int rbase = t >> 3;                              // 0..31
  const int vd0   = (t & 7) * 8;
  const int kA    = (rbase & 15) + ((rbase >> 4) << 5);  // {0..15, 32..47}
  const int vsig2 = (((rbase & 15) << 2) + ((rbase >> 4) << 1)) * 2; // byte pos of sigma(kA)
  const int vswz  = (t & 7) << 4;  // = ((row>>3)&7)<<4 for rows vd0..vd0+7
  uint4 kregA, kregB, vregA, vregB;
  kregA = *(const uint4*)&kqv[(jlo + krow0) * N3 + h * HD + kd0];
  kregB = *(const uint4*)&kqv[(jlo + krow1) * N3 + h * HD + kd0];
  vregA = *(const uint4*)&kqv[(jlo + kA) * N3 + 2 * DM + h * HD + vd0];
  vregB = *(const uint4*)&kqv[(jlo + kA + 16) * N3 + 2 * DM + h * HD + vd0];

  for (int b = 0; b < nblk; ++b) {
    const int j0 = jlo + b * 64;
    __syncthreads();   // prev iter's K/V readers done before overwrite
    // ---- LDS fill from prefetched registers ----
    *(uint4*)&Ks[krow0 * 72 + kd0] = kregA;
    *(uint4*)&Ks[krow1 * 72 + kd0] = kregB;
    {
      const unsigned short* pa = (const unsigned short*)&vregA;
      const unsigned short* pb = (const unsigned short*)&vregB;
      char* vbase = (char*)Vt;
#pragma unroll
      for (int e = 0; e < 8; ++e) {
        unsigned int pack = (unsigned int)pa[e] | ((unsigned int)pb[e] << 16);
        *(unsigned int*)(vbase + (vd0 + e) * 144 + (vsig2 ^ vswz)) = pack;
      }
    }
    __syncthreads();   // nothing outstanding here: prefetch not yet issued

    // ---- issue next block's prefetch NOW (covered by compute below) ----
    if (b + 1 < nblk) {
      const int jn = j0 + 64;
      kregA = *(const uint4*)&kqv[(jn + krow0) * N3 + h * HD + kd0];
      kregB = *(const uint4*)&kqv[(jn + krow1) * N3 + h * HD + kd0];
      vregA = *(const uint4*)&kqv[(jn + kA) * N3 + 2 * DM + h * HD + vd0];
      vregB = *(const uint4*)&kqv[(jn + kA + 16) * N3 + 2 * DM + h * HD + vd0];
    }

    // ---- S = Q*K^T : 4 n-tiles x 2 k-steps ----
    float4v sacc[4] = {};
#pragma unroll
    for (int ks2 = 0; ks2 < 2; ++ks2)
#pragma unroll
      for (int nt = 0; nt < 4; ++nt) {
        short8 bk = *(const short8*)&Ks[(nt * 16 + l15) * 72 + ks2 * 32 + quad * 8];
        sacc[nt] = __builtin_amdgcn_mfma_f32_16x16x32_bf16(aq[ks2], bk, sacc[nt], 0, 0, 0);
      }

    // ---- fixed-max softmax: p = exp2(x), masked -> 0 ----
    // Lane computes S[q][k = nt*16+l15]; stored at p = sigma(k) = l15*4 + nt.
    const int dbase = (i0 + wave * 16 + quad * 4) - (j0 + l15);
    const float s16 = nslope2 * -16.0f;   // bias step per nt
    const int psbase = (wave * 16 + quad * 4) * 72 + l15 * 4;
#pragma unroll
    for (int r = 0; r < 4; ++r) {
      float bias = nslope2 * (float)(dbase + r);
      int rel = dbase + r;
      short4v pk;
#pragma unroll
      for (int nt = 0; nt < 4; ++nt) {
        float x = fmaf(sacc[nt][r], qscale, bias);
        x = ((unsigned)rel <= (unsigned)WIN) ? x : -200.0f;  // exp2(-200)==0
        __hip_bfloat16 hb = __float2bfloat16(exp2f(x));
        pk[nt] = *reinterpret_cast<const short*>(&hb);
        bias += s16;
        rel -= 16;
      }
      *(short4v*)&Ps[psbase + r * 72] = pk;
    }
    // no barrier: Ps strip is wave-private

    // ---- O += P*V (dt 0..3) ; l += P*1 (dt 4, ones-row of Vt) ----
#pragma unroll
    for (int ks = 0; ks < 64; ks += 32) {
      short8 ap = *(const short8*)&Ps[(wave * 16 + l15) * 72 + ks + quad * 8];
#pragma unroll
      for (int dt = 0; dt < 5; ++dt) {
        const int vrow = dt * 16 + l15;
        const short8 bv = *(const short8*)((const char*)Vt + vrow * 144 +
            ((ks * 2 + (quad << 4)) ^ (((vrow >> 3) & 7) << 4)));
        o[dt] = __builtin_amdgcn_mfma_f32_16x16x32_bf16(ap, bv, o[dt], 0, 0, 0);
      }
    }
  }

  // ---- epilogue: l lives in o[4] col 0 (lane l15==0 of each quad group) ----
#pragma unroll
  for (int r = 0; r < 4; ++r) {
    const float l = __shfl(o[4][r], quad * 16, 64);   // broadcast from l15==0 lane
    const float inv_l = 1.0f / l;    // l >= 2^-2: diagonal key j=i always valid
    const int row = i0 + wave * 16 + quad * 4 + r;
#pragma unroll
    for (int dt = 0; dt < 4; ++dt) {
      const int idx = row * DM + h * HD + dt * 16 + l15;
      const float v = o[dt][r] * inv_l;
      if (fl) ((float*)out)[idx] = v;
      else    ((__hip_bfloat16*)out)[idx] = __float2bfloat16(v);
    }
  }
}

// ---------------------------------------------------------------------------
extern "C" void kernel_launch(void* const* d_in, const int* in_sizes, int n_in,
                              void* d_out, int out_size, void* d_ws, size_t ws_size,
                              hipStream_t stream) {
  char* ws = (char*)d_ws;
  __hip_bfloat16* wt  = (__hip_bfloat16*)(ws + 4096);          // 6 MB
  __hip_bfloat16* kqv = (__hip_bfloat16*)(ws + 4096 + 6291456);// 24 MB
  // xb lives in d_out's first 8 MB: dead until attn's epilogue overwrites all
  // of d_out, and gemm_kqv (the only xb reader) completes before attn runs.
  __hip_bfloat16* xb  = (__hip_bfloat16*)d_out;

  hipLaunchKernelGGL(prep, dim3(2048 + 768), dim3(256), 0, stream,
                     d_in[0], d_in[1], xb, wt);
  hipLaunchKernelGGL(gemm_kqv, dim3(16, 32), dim3(512), 0, stream, xb, wt, kqv);
  hipLaunchKernelGGL(attn, dim3(64, 16), dim3(256), 0, stream,
                     kqv, (const unsigned short*)d_in[0], d_out);
}